// Round 8
// baseline (232.832 us; speedup 1.0000x reference)
//
#include <hip/hip_runtime.h>

// Problem constants (from reference): N=65536 rows, A=512 features, C=1000 classes.
constexpr int N_ROWS  = 65536;
constexpr int N_FEAT  = 512;
constexpr int N_FEAT4 = N_FEAT / 4;   // float4 per row = 128
constexpr int N_CLS   = 1000;
constexpr int LIST_CAP = 2048;        // >> max class count (~100 for this input)

// Single-kernel design: block c scans the (L2/L3-resident, 256 KB) label array
// to collect its own row list in LDS — replaces hist+scan+scatter dispatches
// and the perm round-trip. Then gathers feature rows (each row read exactly
// once device-wide, 1 KB contiguous per wave) and applies the fused epilogue.
__global__ __launch_bounds__(256) void estimator_onepass(
    const float* __restrict__ features,
    const int*   __restrict__ labels,
    const float* __restrict__ count,
    const float* __restrict__ mean,
    const float* __restrict__ cov,
    float*       __restrict__ out)
{
    const int c = blockIdx.x;          // class
    const int t = threadIdx.x;
    const int half = t >> 7;           // which row of the pair
    const int col  = t & 127;          // float4 column index

    __shared__ int cnt;
    __shared__ int list[LIST_CAP];
    __shared__ float4 red_s[128];
    __shared__ float4 red_q[128];

    // ---- Phase A: collect row indices with label == c (order-insensitive) ----
    if (t == 0) cnt = 0;
    __syncthreads();
    const int4* __restrict__ l4 = (const int4*)labels;
    for (int i = t; i < N_ROWS / 4; i += 256) {
        const int4 v = l4[i];
        const int r = i * 4;
        if (v.x == c) { int p = atomicAdd(&cnt, 1); if (p < LIST_CAP) list[p] = r;     }
        if (v.y == c) { int p = atomicAdd(&cnt, 1); if (p < LIST_CAP) list[p] = r + 1; }
        if (v.z == c) { int p = atomicAdd(&cnt, 1); if (p < LIST_CAP) list[p] = r + 2; }
        if (v.w == c) { int p = atomicAdd(&cnt, 1); if (p < LIST_CAP) list[p] = r + 3; }
    }
    __syncthreads();
    const int n = min(cnt, LIST_CAP);

    // ---- Phase B: gather feature rows, accumulate sum & sum-of-squares ----
    const float4* __restrict__ f4 = (const float4*)features;
    float s0 = 0.f, s1 = 0.f, s2 = 0.f, s3 = 0.f;
    float q0 = 0.f, q1 = 0.f, q2 = 0.f, q3 = 0.f;

    int j = 0;
    for (; j + 16 <= n; j += 16) {     // 8 independent 16B loads/lane
        const int r0 = list[j +  0 + half], r1 = list[j +  2 + half];
        const int r2 = list[j +  4 + half], r3 = list[j +  6 + half];
        const int r4 = list[j +  8 + half], r5 = list[j + 10 + half];
        const int r6 = list[j + 12 + half], r7 = list[j + 14 + half];
        const float4 v0 = f4[(size_t)r0 * N_FEAT4 + col];
        const float4 v1 = f4[(size_t)r1 * N_FEAT4 + col];
        const float4 v2 = f4[(size_t)r2 * N_FEAT4 + col];
        const float4 v3 = f4[(size_t)r3 * N_FEAT4 + col];
        const float4 v4 = f4[(size_t)r4 * N_FEAT4 + col];
        const float4 v5 = f4[(size_t)r5 * N_FEAT4 + col];
        const float4 v6 = f4[(size_t)r6 * N_FEAT4 + col];
        const float4 v7 = f4[(size_t)r7 * N_FEAT4 + col];
        #define ACC(v) \
            s0 += v.x; q0 = fmaf(v.x, v.x, q0); \
            s1 += v.y; q1 = fmaf(v.y, v.y, q1); \
            s2 += v.z; q2 = fmaf(v.z, v.z, q2); \
            s3 += v.w; q3 = fmaf(v.w, v.w, q3);
        ACC(v0) ACC(v1) ACC(v2) ACC(v3) ACC(v4) ACC(v5) ACC(v6) ACC(v7)
        #undef ACC
    }
    if (j < n) {                       // weighted remainder (<=15 rows)
        #pragma unroll
        for (int u = 0; u < 8; ++u) {
            const int idx = j + 2 * u + half;
            const int r = (idx < n) ? list[idx] : list[j];
            const float w = (idx < n) ? 1.f : 0.f;
            const float4 v = f4[(size_t)r * N_FEAT4 + col];
            const float vx = v.x * w, vy = v.y * w, vz = v.z * w, vw = v.w * w;
            s0 += vx; q0 = fmaf(vx, v.x, q0);
            s1 += vy; q1 = fmaf(vy, v.y, q1);
            s2 += vz; q2 = fmaf(vz, v.z, q2);
            s3 += vw; q3 = fmaf(vw, v.w, q3);
        }
    }

    // ---- Phase C: cross-half reduce + fused epilogue ----
    __syncthreads();
    if (half == 1) {
        red_s[col] = make_float4(s0, s1, s2, s3);
        red_q[col] = make_float4(q0, q1, q2, q3);
    }
    __syncthreads();
    if (half == 0) {
        const float4 rs = red_s[col], rq = red_q[col];
        s0 += rs.x; s1 += rs.y; s2 += rs.z; s3 += rs.w;
        q0 += rq.x; q1 += rq.y; q2 += rq.z; q3 += rq.w;

        const float fn  = (float)n;
        const float amt = (n > 0) ? fn : 1.0f;
        const float inv = 1.0f / amt;
        const float a0 = s0 * inv, a1 = s1 * inv, a2 = s2 * inv, a3 = s3 * inv;
        const float vr0 = q0 * inv - a0 * a0;   // E[x^2]-E[x]^2 == segsum((x-ave)^2)/amt
        const float vr1 = q1 * inv - a1 * a1;
        const float vr2 = q2 * inv - a2 * a2;
        const float vr3 = q3 * inv - a3 * a3;

        const float cnt_c = count[c];
        const float denom = fn + cnt_c;
        const float w     = (denom == 0.f) ? 0.f : fn / denom;
        const float omw   = 1.0f - w;

        const float4 mv = ((const float4*)mean)[c * N_FEAT4 + col];
        const float4 cv = ((const float4*)cov)[c * N_FEAT4 + col];
        const float d0 = mv.x - a0, d1 = mv.y - a1, d2 = mv.z - a2, d3 = mv.w - a3;

        float4 covn, meann;
        covn.x  = cv.x * omw + vr0 * w + w * omw * d0 * d0;
        covn.y  = cv.y * omw + vr1 * w + w * omw * d1 * d1;
        covn.z  = cv.z * omw + vr2 * w + w * omw * d2 * d2;
        covn.w  = cv.w * omw + vr3 * w + w * omw * d3 * d3;
        meann.x = mv.x * omw + a0 * w;
        meann.y = mv.y * omw + a1 * w;
        meann.z = mv.z * omw + a2 * w;
        meann.w = mv.w * omw + a3 * w;

        ((float4*)out)[c * N_FEAT4 + col] = covn;                      // cov_new  [C,A]
        ((float4*)(out + N_CLS * N_FEAT))[c * N_FEAT4 + col] = meann;  // mean_new [C,A]
        if (t == 0) out[2 * N_CLS * N_FEAT + c] = cnt_c + fn;          // count_new [C]
    }
}

extern "C" void kernel_launch(void* const* d_in, const int* in_sizes, int n_in,
                              void* d_out, int out_size, void* d_ws, size_t ws_size,
                              hipStream_t stream) {
    const float* features = (const float*)d_in[0];
    const int*   labels   = (const int*)d_in[1];
    const float* count    = (const float*)d_in[2];
    const float* mean     = (const float*)d_in[3];
    const float* cov      = (const float*)d_in[4];
    float* out = (float*)d_out;

    estimator_onepass<<<N_CLS, 256, 0, stream>>>(features, labels, count,
                                                 mean, cov, out);
}

// Round 9
// 215.436 us; speedup vs baseline: 1.0807x; 1.0807x over previous
//
#include <hip/hip_runtime.h>

// Problem constants (from reference): N=65536 rows, A=512 features, C=1000 classes.
constexpr int N_ROWS  = 65536;
constexpr int N_FEAT  = 512;
constexpr int N_FEAT4 = N_FEAT / 4;   // float4 per row = 128
constexpr int N_CLS   = 1000;
constexpr int LIST_CAP = 2048;        // >> max class count (~106 = 65.5 + 5 sigma)

// Single-dispatch design. Block c:
//   Phase A: scan all 65536 labels (L2-resident, 256 KB) with 4-deep batched
//            int4 loads + wave-prefix compaction (1 LDS atomic per wave-step,
//            not per match) -> row list in LDS.
//   Phase B: gather feature rows (each row read once device-wide, wave reads
//            1 KB contiguous) with 8/4-load tiers for MLP.
//   Phase C: cross-half LDS reduce + fused EMA epilogue.
__global__ __launch_bounds__(256) void estimator_onepass(
    const float* __restrict__ features,
    const int*   __restrict__ labels,
    const float* __restrict__ count,
    const float* __restrict__ cls_mean,
    const float* __restrict__ cls_cov,
    float*       __restrict__ out)
{
    const int c = blockIdx.x;          // class
    const int t = threadIdx.x;
    const int wave = t >> 6;
    const int lane = t & 63;

    __shared__ int cnt;
    __shared__ int list[LIST_CAP];
    __shared__ float4 red_s[128];
    __shared__ float4 red_q[128];

    if (t == 0) cnt = 0;
    __syncthreads();

    // ---- Phase A: wave-compaction label scan ----
    // Each wave owns 16384 labels = 4096 int4; per step a wave consumes
    // 64 lanes x 4 int4 = 256 int4 (1024 labels); 16 steps total.
    {
        const int4* __restrict__ l4 = (const int4*)labels;
        const int waveBase4 = wave * 4096;
        for (int s = 0; s < 16; ++s) {
            const int base4 = waveBase4 + s * 256 + lane;
            const int4 va = l4[base4];          // 4 batched 16B loads
            const int4 vb = l4[base4 + 64];
            const int4 vc = l4[base4 + 128];
            const int4 vd = l4[base4 + 192];
            unsigned mask = 0;
            mask |= (va.x == c) ? 0x0001u : 0u; mask |= (va.y == c) ? 0x0002u : 0u;
            mask |= (va.z == c) ? 0x0004u : 0u; mask |= (va.w == c) ? 0x0008u : 0u;
            mask |= (vb.x == c) ? 0x0010u : 0u; mask |= (vb.y == c) ? 0x0020u : 0u;
            mask |= (vb.z == c) ? 0x0040u : 0u; mask |= (vb.w == c) ? 0x0080u : 0u;
            mask |= (vc.x == c) ? 0x0100u : 0u; mask |= (vc.y == c) ? 0x0200u : 0u;
            mask |= (vc.z == c) ? 0x0400u : 0u; mask |= (vc.w == c) ? 0x0800u : 0u;
            mask |= (vd.x == c) ? 0x1000u : 0u; mask |= (vd.y == c) ? 0x2000u : 0u;
            mask |= (vd.z == c) ? 0x4000u : 0u; mask |= (vd.w == c) ? 0x8000u : 0u;

            const int m = __popc(mask);
            int inc = m;                         // wave-inclusive scan of counts
            #pragma unroll
            for (int d = 1; d < 64; d <<= 1) {
                const int x = __shfl_up(inc, d, 64);
                if (lane >= d) inc += x;
            }
            int basep = 0;
            if (lane == 63) basep = atomicAdd(&cnt, inc);   // inc@63 == wave total
            basep = __shfl(basep, 63, 64);
            int off = basep + inc - m;           // exclusive offset for this lane
            unsigned mm = mask;
            while (mm) {
                const int k = __ffs(mm) - 1; mm &= mm - 1;
                const int row = (base4 + (k >> 2) * 64) * 4 + (k & 3);
                if (off < LIST_CAP) list[off] = row;
                ++off;
            }
        }
    }
    __syncthreads();
    const int n = min(cnt, LIST_CAP);

    // ---- Phase B: gather + accumulate sum / sum-of-squares ----
    const int half = t >> 7;          // which row of the interleaved pair
    const int col  = t & 127;         // float4 column
    const float4* __restrict__ f4 = (const float4*)features;

    float s0 = 0.f, s1 = 0.f, s2 = 0.f, s3 = 0.f;
    float q0 = 0.f, q1 = 0.f, q2 = 0.f, q3 = 0.f;

    #define ACC(v) \
        s0 += v.x; q0 = fmaf(v.x, v.x, q0); \
        s1 += v.y; q1 = fmaf(v.y, v.y, q1); \
        s2 += v.z; q2 = fmaf(v.z, v.z, q2); \
        s3 += v.w; q3 = fmaf(v.w, v.w, q3);

    int j = 0;
    for (; j + 16 <= n; j += 16) {     // tier 1: 8 independent 16B loads/lane
        const int r0 = list[j +  0 + half], r1 = list[j +  2 + half];
        const int r2 = list[j +  4 + half], r3 = list[j +  6 + half];
        const int r4 = list[j +  8 + half], r5 = list[j + 10 + half];
        const int r6 = list[j + 12 + half], r7 = list[j + 14 + half];
        const float4 v0 = f4[(size_t)r0 * N_FEAT4 + col];
        const float4 v1 = f4[(size_t)r1 * N_FEAT4 + col];
        const float4 v2 = f4[(size_t)r2 * N_FEAT4 + col];
        const float4 v3 = f4[(size_t)r3 * N_FEAT4 + col];
        const float4 v4 = f4[(size_t)r4 * N_FEAT4 + col];
        const float4 v5 = f4[(size_t)r5 * N_FEAT4 + col];
        const float4 v6 = f4[(size_t)r6 * N_FEAT4 + col];
        const float4 v7 = f4[(size_t)r7 * N_FEAT4 + col];
        ACC(v0) ACC(v1) ACC(v2) ACC(v3) ACC(v4) ACC(v5) ACC(v6) ACC(v7)
    }
    for (; j + 8 <= n; j += 8) {       // tier 2: 4 independent loads/lane
        const int r0 = list[j + 0 + half], r1 = list[j + 2 + half];
        const int r2 = list[j + 4 + half], r3 = list[j + 6 + half];
        const float4 v0 = f4[(size_t)r0 * N_FEAT4 + col];
        const float4 v1 = f4[(size_t)r1 * N_FEAT4 + col];
        const float4 v2 = f4[(size_t)r2 * N_FEAT4 + col];
        const float4 v3 = f4[(size_t)r3 * N_FEAT4 + col];
        ACC(v0) ACC(v1) ACC(v2) ACC(v3)
    }
    if (j < n) {                       // weighted tail (<=7 rows); row 0 safe filler
        #pragma unroll
        for (int u = 0; u < 4; ++u) {
            const int idx = j + 2 * u + half;
            const int r = (idx < n) ? list[idx] : 0;
            const float w = (idx < n) ? 1.f : 0.f;
            const float4 v = f4[(size_t)r * N_FEAT4 + col];
            const float vx = v.x * w, vy = v.y * w, vz = v.z * w, vw = v.w * w;
            s0 += vx; q0 = fmaf(vx, v.x, q0);
            s1 += vy; q1 = fmaf(vy, v.y, q1);
            s2 += vz; q2 = fmaf(vz, v.z, q2);
            s3 += vw; q3 = fmaf(vw, v.w, q3);
        }
    }
    #undef ACC

    // ---- Phase C: cross-half reduce + fused epilogue ----
    __syncthreads();
    if (half == 1) {
        red_s[col] = make_float4(s0, s1, s2, s3);
        red_q[col] = make_float4(q0, q1, q2, q3);
    }
    __syncthreads();
    if (half == 0) {
        const float4 rs = red_s[col], rq = red_q[col];
        s0 += rs.x; s1 += rs.y; s2 += rs.z; s3 += rs.w;
        q0 += rq.x; q1 += rq.y; q2 += rq.z; q3 += rq.w;

        const float fn  = (float)n;
        const float amt = (n > 0) ? fn : 1.0f;
        const float inv = 1.0f / amt;
        const float a0 = s0 * inv, a1 = s1 * inv, a2 = s2 * inv, a3 = s3 * inv;
        const float vr0 = q0 * inv - a0 * a0;   // E[x^2]-E[x]^2 == segsum((x-ave)^2)/amt
        const float vr1 = q1 * inv - a1 * a1;
        const float vr2 = q2 * inv - a2 * a2;
        const float vr3 = q3 * inv - a3 * a3;

        const float cnt_c = count[c];
        const float denom = fn + cnt_c;
        const float w     = (denom == 0.f) ? 0.f : fn / denom;
        const float omw   = 1.0f - w;

        const float4 mv = ((const float4*)cls_mean)[c * N_FEAT4 + col];
        const float4 cv = ((const float4*)cls_cov)[c * N_FEAT4 + col];
        const float d0 = mv.x - a0, d1 = mv.y - a1, d2 = mv.z - a2, d3 = mv.w - a3;

        float4 covn, meann;
        covn.x  = cv.x * omw + vr0 * w + w * omw * d0 * d0;
        covn.y  = cv.y * omw + vr1 * w + w * omw * d1 * d1;
        covn.z  = cv.z * omw + vr2 * w + w * omw * d2 * d2;
        covn.w  = cv.w * omw + vr3 * w + w * omw * d3 * d3;
        meann.x = mv.x * omw + a0 * w;
        meann.y = mv.y * omw + a1 * w;
        meann.z = mv.z * omw + a2 * w;
        meann.w = mv.w * omw + a3 * w;

        ((float4*)out)[c * N_FEAT4 + col] = covn;                      // cov_new  [C,A]
        ((float4*)(out + N_CLS * N_FEAT))[c * N_FEAT4 + col] = meann;  // mean_new [C,A]
        if (t == 0) out[2 * N_CLS * N_FEAT + c] = cnt_c + fn;          // count_new [C]
    }
}

extern "C" void kernel_launch(void* const* d_in, const int* in_sizes, int n_in,
                              void* d_out, int out_size, void* d_ws, size_t ws_size,
                              hipStream_t stream) {
    const float* features = (const float*)d_in[0];
    const int*   labels   = (const int*)d_in[1];
    const float* count    = (const float*)d_in[2];
    const float* mean     = (const float*)d_in[3];
    const float* cov      = (const float*)d_in[4];
    float* out = (float*)d_out;

    estimator_onepass<<<N_CLS, 256, 0, stream>>>(features, labels, count,
                                                 mean, cov, out);
}